// Round 7
// baseline (347.781 us; speedup 1.0000x reference)
//
#include <hip/hip_runtime.h>
#include <hip/hip_fp16.h>

constexpr int TPB = 256;
constexpr int SH = 9;          // bucket = 512 consecutive destinations
constexpr int BD = 1 << SH;    // 512 dests per bucket (max 512 buckets -> n <= 262144)
constexpr int CHUNK = 4096;    // edges per binning block
constexpr int RMASK = (1 << 23) - 1;  // row in low 23 bits, local dest in high 9

typedef _Float16 half8 __attribute__((ext_vector_type(8)));
typedef float float4v __attribute__((ext_vector_type(4)));

__device__ __forceinline__ int wave_incl_scan(int x, int lane) {
#pragma unroll
  for (int d = 1; d < 64; d <<= 1) {
    int y = __shfl_up(x, d);
    if (lane >= d) x += y;
  }
  return x;
}

// ---------------- binned CSR build (grouped by destination) ----------------
// Edge entries are packed ints: (local_dest_in_bucket << 23) | src_row.

__global__ void bin_kernel(const int* __restrict__ row, const int* __restrict__ col,
                           int* __restrict__ bcur, int* __restrict__ binned,
                           int e, int nb, int cap) {
  __shared__ int h[512];
  __shared__ int base[512];
  for (int i = threadIdx.x; i < nb; i += TPB) h[i] = 0;
  __syncthreads();
  int cb = blockIdx.x * CHUNK;
  int lim = min(cb + CHUNK, e);
  for (int i = cb + threadIdx.x; i < lim; i += TPB)
    atomicAdd(&h[col[i] >> SH], 1);
  __syncthreads();
  for (int i = threadIdx.x; i < nb; i += TPB) {
    int c = h[i];
    base[i] = c ? (i * cap + atomicAdd(&bcur[i], c)) : 0;
    h[i] = 0;  // reuse as local cursor
  }
  __syncthreads();
  for (int i = cb + threadIdx.x; i < lim; i += TPB) {
    int c = col[i];  // L2-hot re-read of this block's own chunk
    int b = c >> SH;
    int p = base[b] + atomicAdd(&h[b], 1);
    binned[p] = ((c & (BD - 1)) << 23) | row[i];
  }
}

// per bucket: fine counts -> scan -> offs2/dinv -> place (fused; binned stays L2-hot)
__global__ __launch_bounds__(512) void count_place_kernel(
    const int* __restrict__ binned, const int* __restrict__ bcnt, int cap,
    int2* __restrict__ offs2, float* __restrict__ dinv, int* __restrict__ csr, int n) {
  __shared__ int cnt[BD];
  __shared__ int wsum[8];
  int t = threadIdx.x, lane = t & 63, wv = t >> 6;
  int b = blockIdx.x;
  int c0 = b << SH;
  int ndst = min(BD, n - c0);
  cnt[t] = 0;
  __syncthreads();
  int beg = b * cap;
  int end = beg + bcnt[b];
  for (int i = beg + t; i < end; i += 512)
    atomicAdd(&cnt[(unsigned)binned[i] >> 23], 1);
  __syncthreads();
  int v = cnt[t];
  int ps = wave_incl_scan(v, lane);
  if (lane == 63) wsum[wv] = ps;
  __syncthreads();
  int woff = 0;
#pragma unroll
  for (int w = 0; w < 8; w++) woff += (w < wv) ? wsum[w] : 0;
  int ex = woff + ps - v;
  if (t < ndst) {
    offs2[c0 + t] = make_int2(beg + ex, beg + ex + v);
    dinv[c0 + t] = rsqrtf(1.0f + (float)v);  // deg = incoming + self-loop
  }
  __syncthreads();  // counts consumed; reuse cnt[] as cursors
  cnt[t] = beg + ex;
  __syncthreads();
  for (int i = beg + t; i < end; i += 512) {
    int pv = binned[i];
    int p = atomicAdd(&cnt[(unsigned)pv >> 23], 1);
    csr[p] = pv;  // packed entry passes through unchanged
  }
}

// ---------------- fused weight packing (+ bcur zero) ----------------

template <int K, int M, int CT, int KT>
__device__ __forceinline__ void pack_one(const float* __restrict__ W,
                                         _Float16* __restrict__ P, int idx) {
  if (idx >= CT * KT * 64 * 8) return;
  int j = idx & 7;
  int lane = (idx >> 3) & 63;
  int f = idx >> 9;
  int kt = f % KT, ct = f / KT;
  int c = ct * 16 + (lane & 15);
  int k = kt * 32 + (lane >> 4) * 8 + j;
  float v = (c < M) ? W[k * M + c] : 0.f;
  P[idx] = (_Float16)v;
}

__global__ __launch_bounds__(256) void pack_all_kernel(
    const float* __restrict__ W1, const float* __restrict__ W2,
    const float* __restrict__ W3, _Float16* __restrict__ P1,
    _Float16* __restrict__ P2, _Float16* __restrict__ P3, int* __restrict__ bcur) {
  int blk = blockIdx.x, t = threadIdx.x;
  if (blk < 32) {
    pack_one<128, 64, 4, 4>(W1, P1, blk * 256 + t);
  } else if (blk < 48) {
    pack_one<64, 64, 4, 2>(W2, P2, (blk - 32) * 256 + t);
  } else if (blk < 60) {
    pack_one<64, 40, 3, 2>(W3, P3, (blk - 48) * 256 + t);
  } else {
    bcur[t] = 0;
    bcur[t + 256] = 0;
  }
}

// ---------------- layer-1 MFMA GEMM (fp32 in, fp16 out, dinv pre-scale) -----

template <int K, int M, int CT>
__global__ __launch_bounds__(256) void gemm_mfma_f32in(const float* __restrict__ x,
                                                       const _Float16* __restrict__ PW,
                                                       const float* __restrict__ dinv,
                                                       _Float16* __restrict__ out, int n) {
  constexpr int KT = K / 32;
  int lane = threadIdx.x & 63, wv = threadIdx.x >> 6;
  int m = lane & 15, q = lane >> 4;
  int row0w = blockIdx.x * 64 + wv * 16;
  int arow = row0w + m;
  int ar = arow < n ? arow : n - 1;  // clamp; stores are guarded
  const half8* pw = (const half8*)PW;

  float4v acc[CT];
#pragma unroll
  for (int ct = 0; ct < CT; ct++) acc[ct] = (float4v){0.f, 0.f, 0.f, 0.f};

#pragma unroll
  for (int kt = 0; kt < KT; kt++) {
    const float* xp = x + (size_t)ar * K + kt * 32 + q * 8;
    float4 x0 = *(const float4*)xp;
    float4 x1 = *(const float4*)(xp + 4);
    half8 a;
    a[0] = (_Float16)x0.x; a[1] = (_Float16)x0.y;
    a[2] = (_Float16)x0.z; a[3] = (_Float16)x0.w;
    a[4] = (_Float16)x1.x; a[5] = (_Float16)x1.y;
    a[6] = (_Float16)x1.z; a[7] = (_Float16)x1.w;
#pragma unroll
    for (int ct = 0; ct < CT; ct++) {
      half8 b = pw[(ct * KT + kt) * 64 + lane];
      acc[ct] = __builtin_amdgcn_mfma_f32_16x16x32_f16(a, b, acc[ct], 0, 0, 0);
    }
  }
  // D layout: col = lane&15, row = q*4 + reg
  int r0 = row0w + q * 4;
  float dv[4];
#pragma unroll
  for (int reg = 0; reg < 4; reg++) dv[reg] = (r0 + reg < n) ? dinv[r0 + reg] : 0.f;
#pragma unroll
  for (int ct = 0; ct < CT; ct++) {
    int c = ct * 16 + m;
    if (c < M) {
#pragma unroll
      for (int reg = 0; reg < 4; reg++) {
        int r = r0 + reg;
        if (r < n) out[(size_t)r * M + c] = (_Float16)(acc[ct][reg] * dv[reg]);
      }
    }
  }
}

// ---------------- aggregation: 8-lane group owns TWO adjacent dests ----------
// Group g owns dests base+2g, base+2g+1 whose csr runs are CONTIGUOUS
// (dest-sorted within a bucket; 128-dest blocks never cross the 512-dest
// bucket boundary). One combined batch-8 loop: per batch, 8 independent 16B
// gathers issue first, then the NEXT batch's csr indices load (prefetch
// hides index latency under gather latency), then accumulate. The per-batch
// group-uniform split point s = d - b routes edge j to accA (j<s) or accB.
// No atomics, no shfl, perfect batch packing across the dest pair.

__device__ __forceinline__ void h8_unpack(uint4 u, float* f) {
  __half2 h0 = *(__half2*)&u.x, h1 = *(__half2*)&u.y;
  __half2 h2 = *(__half2*)&u.z, h3 = *(__half2*)&u.w;
  float2 f0 = __half22float2(h0), f1 = __half22float2(h1);
  float2 f2 = __half22float2(h2), f3 = __half22float2(h3);
  f[0] = f0.x; f[1] = f0.y; f[2] = f1.x; f[3] = f1.y;
  f[4] = f2.x; f[5] = f2.y; f[6] = f3.x; f[7] = f3.y;
}

__device__ __forceinline__ uint4 pack_h8v(const float* o) {
  __half2 h0 = __float22half2_rn(make_float2(o[0], o[1]));
  __half2 h1 = __float22half2_rn(make_float2(o[2], o[3]));
  __half2 h2 = __float22half2_rn(make_float2(o[4], o[5]));
  __half2 h3 = __float22half2_rn(make_float2(o[6], o[7]));
  uint4 u;
  u.x = *(unsigned*)&h0;
  u.y = *(unsigned*)&h1;
  u.z = *(unsigned*)&h2;
  u.w = *(unsigned*)&h3;
  return u;
}

__device__ __forceinline__ void agg_pair(
    const uint4* __restrict__ xw4, const int* __restrict__ csr,
    int beg, int d, int end, int fl, float* accA, float* accB) {
  int r[8];
#pragma unroll
  for (int j = 0; j < 8; j++) {
    int idx = beg + j;
    r[j] = (idx < end) ? (csr[idx] & RMASK) : 0;
  }
#pragma unroll 1
  for (int b = beg; b < end; b += 8) {
    int cnt = end - b;  // group-uniform
    // 1) issue gathers for current batch (addresses ready from last iter)
    uint4 u[8];
#pragma unroll
    for (int j = 0; j < 8; j++)
      if (j < cnt) u[j] = xw4[(size_t)r[j] * 8 + fl];
    // 2) prefetch next batch's csr indices (independent; stays in flight
    //    through the accumulate phase below)
    int rn[8];
    int bn = b + 8;
#pragma unroll
    for (int j = 0; j < 8; j++) {
      int idx = bn + j;
      rn[j] = (idx < end) ? (csr[idx] & RMASK) : 0;
    }
    // 3) accumulate, routing by the group-uniform split point
    int s = d - b;  // j < s -> dest A, else dest B
#pragma unroll
    for (int j = 0; j < 8; j++) {
      if (j < cnt) {
        float f[8];
        h8_unpack(u[j], f);
        if (j < s) {
#pragma unroll
          for (int k = 0; k < 8; k++) accA[k] += f[k];
        } else {
#pragma unroll
          for (int k = 0; k < 8; k++) accB[k] += f[k];
        }
      }
    }
#pragma unroll
    for (int j = 0; j < 8; j++) r[j] = rn[j];
  }
}

// ---------------- standalone mid aggregation (layer-2) ----------------
// out = relu((acc+self)*di + b2) * di   (pre-scaled for the layer-3 pre-agg)

__global__ __launch_bounds__(512) void agg_mid_kernel(
    const uint4* __restrict__ xw4, const float* __restrict__ dinv,
    const int* __restrict__ csr, const int2* __restrict__ offs2,
    const float* __restrict__ bias, uint4* __restrict__ out4, int n) {
  int t = threadIdx.x;
  int g = t >> 3, fl = t & 7;
  int i0 = blockIdx.x * 128 + 2 * g, i1 = i0 + 1;
  if (i0 >= n) return;
  int2 oeA = offs2[i0];  // group-broadcast load
  int beg = oeA.x, d = oeA.y;
  int end = (i1 < n) ? offs2[i1].y : d;  // contiguous: offs2[i1].x == d
  float accA[8] = {0.f, 0.f, 0.f, 0.f, 0.f, 0.f, 0.f, 0.f};
  float accB[8] = {0.f, 0.f, 0.f, 0.f, 0.f, 0.f, 0.f, 0.f};
  agg_pair(xw4, csr, beg, d, end, fl, accA, accB);

  const float4* b4 = (const float4*)bias;
  float4 ba = b4[fl * 2], bb = b4[fl * 2 + 1];
  {
    float di = dinv[i0];
    uint4 sv = xw4[(size_t)i0 * 8 + fl];  // self-loop row (pre-scaled)
    float sf[8];
    h8_unpack(sv, sf);
    float o[8];
    o[0] = fmaxf((accA[0] + sf[0]) * di + ba.x, 0.f) * di;
    o[1] = fmaxf((accA[1] + sf[1]) * di + ba.y, 0.f) * di;
    o[2] = fmaxf((accA[2] + sf[2]) * di + ba.z, 0.f) * di;
    o[3] = fmaxf((accA[3] + sf[3]) * di + ba.w, 0.f) * di;
    o[4] = fmaxf((accA[4] + sf[4]) * di + bb.x, 0.f) * di;
    o[5] = fmaxf((accA[5] + sf[5]) * di + bb.y, 0.f) * di;
    o[6] = fmaxf((accA[6] + sf[6]) * di + bb.z, 0.f) * di;
    o[7] = fmaxf((accA[7] + sf[7]) * di + bb.w, 0.f) * di;
    out4[(size_t)i0 * 8 + fl] = pack_h8v(o);
  }
  if (i1 < n) {
    float di = dinv[i1];
    uint4 sv = xw4[(size_t)i1 * 8 + fl];
    float sf[8];
    h8_unpack(sv, sf);
    float o[8];
    o[0] = fmaxf((accB[0] + sf[0]) * di + ba.x, 0.f) * di;
    o[1] = fmaxf((accB[1] + sf[1]) * di + ba.y, 0.f) * di;
    o[2] = fmaxf((accB[2] + sf[2]) * di + ba.z, 0.f) * di;
    o[3] = fmaxf((accB[3] + sf[3]) * di + ba.w, 0.f) * di;
    o[4] = fmaxf((accB[4] + sf[4]) * di + bb.x, 0.f) * di;
    o[5] = fmaxf((accB[5] + sf[5]) * di + bb.y, 0.f) * di;
    o[6] = fmaxf((accB[6] + sf[6]) * di + bb.z, 0.f) * di;
    o[7] = fmaxf((accB[7] + sf[7]) * di + bb.w, 0.f) * di;
    out4[(size_t)i1 * 8 + fl] = pack_h8v(o);
  }
}

// ---------------- fused aggregation + MFMA GEMM ----------------
// 512 threads, block owns 128 dest rows. Group-agg (2 dests/group) straight
// into fp16 tileH (stride 72, 16B-aligned rows), one barrier, then 8 waves x
// 16 rows run the K=64 MFMA GEMM.
// FMODE 0 (layers 1->2): agg epilogue relu(acc*di + biasA); gemm out fp16 *dinv[r].
// FMODE 1 (layer 3):     agg epilogue acc*di;               gemm out fp32 + biasG.

template <int M, int CT, int FMODE>
__global__ __launch_bounds__(512) void fused_agg_gemm(
    const uint4* __restrict__ xw4, const float* __restrict__ dinv,
    const int* __restrict__ csr, const int2* __restrict__ offs2,
    const float* __restrict__ biasA, const float* __restrict__ biasG,
    const _Float16* __restrict__ PW, void* __restrict__ outp, int n) {
  constexpr int KT = 2;  // K = 64
  __shared__ _Float16 tileH[128 * 72];
  int t = threadIdx.x;
  int base = blockIdx.x * 128;
  {
    int g = t >> 3, fl = t & 7;
    int i0 = base + 2 * g, i1 = i0 + 1;
    half8 hA = (half8)(_Float16)0.f, hB = (half8)(_Float16)0.f;
    if (i0 < n) {
      int2 oeA = offs2[i0];
      int beg = oeA.x, d = oeA.y;
      int end = (i1 < n) ? offs2[i1].y : d;
      float accA[8] = {0.f, 0.f, 0.f, 0.f, 0.f, 0.f, 0.f, 0.f};
      float accB[8] = {0.f, 0.f, 0.f, 0.f, 0.f, 0.f, 0.f, 0.f};
      agg_pair(xw4, csr, beg, d, end, fl, accA, accB);
      {
        float di = dinv[i0];
        uint4 sv = xw4[(size_t)i0 * 8 + fl];  // self-loop row (pre-scaled)
        float sf[8];
        h8_unpack(sv, sf);
#pragma unroll
        for (int k = 0; k < 8; k++) {
          float f = accA[k] + sf[k];
          f = (FMODE == 0) ? fmaxf(f * di + biasA[fl * 8 + k], 0.f) : f * di;
          hA[k] = (_Float16)f;
        }
      }
      if (i1 < n) {
        float di = dinv[i1];
        uint4 sv = xw4[(size_t)i1 * 8 + fl];
        float sf[8];
        h8_unpack(sv, sf);
#pragma unroll
        for (int k = 0; k < 8; k++) {
          float f = accB[k] + sf[k];
          f = (FMODE == 0) ? fmaxf(f * di + biasA[fl * 8 + k], 0.f) : f * di;
          hB[k] = (_Float16)f;
        }
      }
    }
    *(half8*)&tileH[(2 * g) * 72 + fl * 8] = hA;
    *(half8*)&tileH[(2 * g + 1) * 72 + fl * 8] = hB;
  }
  __syncthreads();

  // ---- MFMA phase: 8 waves x 16 rows = 128 rows, CT column tiles each ----
  int lane = t & 63, wv = t >> 6;
  int m = lane & 15, q = lane >> 4;
  int lrow = wv * 16 + m;
  const half8* pw = (const half8*)PW;
  float4v accd[CT];
#pragma unroll
  for (int ct = 0; ct < CT; ct++) accd[ct] = (float4v){0.f, 0.f, 0.f, 0.f};
#pragma unroll
  for (int kt = 0; kt < KT; kt++) {
    half8 a = *(const half8*)&tileH[lrow * 72 + kt * 32 + q * 8];
#pragma unroll
    for (int ct = 0; ct < CT; ct++) {
      half8 b = pw[(ct * KT + kt) * 64 + lane];
      accd[ct] = __builtin_amdgcn_mfma_f32_16x16x32_f16(a, b, accd[ct], 0, 0, 0);
    }
  }
  int r0 = base + wv * 16 + q * 4;
  if (FMODE == 0) {
    _Float16* out = (_Float16*)outp;
    float dv[4];
#pragma unroll
    for (int reg = 0; reg < 4; reg++) dv[reg] = (r0 + reg < n) ? dinv[r0 + reg] : 0.f;
#pragma unroll
    for (int ct = 0; ct < CT; ct++) {
      int c = ct * 16 + m;
      if (c < M) {
#pragma unroll
        for (int reg = 0; reg < 4; reg++) {
          int r = r0 + reg;
          if (r < n) out[(size_t)r * M + c] = (_Float16)(accd[ct][reg] * dv[reg]);
        }
      }
    }
  } else {
    float* out = (float*)outp;
#pragma unroll
    for (int ct = 0; ct < CT; ct++) {
      int c = ct * 16 + m;
      if (c < M) {
        float bb = biasG[c];
#pragma unroll
        for (int reg = 0; reg < 4; reg++) {
          int r = r0 + reg;
          if (r < n) out[(size_t)r * M + c] = accd[ct][reg] + bb;
        }
      }
    }
  }
}

// ---------------- launcher ----------------

extern "C" void kernel_launch(void* const* d_in, const int* in_sizes, int n_in,
                              void* d_out, int out_size, void* d_ws, size_t ws_size,
                              hipStream_t stream) {
  const float* x  = (const float*)d_in[0];
  const int*   ei = (const int*)d_in[1];
  const float* W1 = (const float*)d_in[2];
  const float* b1 = (const float*)d_in[3];
  const float* W2 = (const float*)d_in[4];
  const float* b2 = (const float*)d_in[5];
  const float* W3 = (const float*)d_in[6];
  const float* b3 = (const float*)d_in[7];

  int n = in_sizes[0] / 128;
  int e = in_sizes[1] / 2;
  const int* rowA = ei;      // edge_index[0] = source
  const int* colA = ei + e;  // edge_index[1] = destination (segment id)

  int nb = (n + BD - 1) >> SH;  // buckets (<= 512)
  int meanb = e / nb;
  int cap = meanb + (meanb / 4 > 1024 ? meanb / 4 : 1024);  // >25 sigma slack
  int nch = (e + CHUNK - 1) / CHUNK;

  size_t off = 0;
  auto alloc = [&](size_t bytes) {
    void* p = (char*)d_ws + off;
    off += (bytes + 255) & ~(size_t)255;
    return p;
  };
  // bufA (n*64*4 B) also aliases the binned edge array (nb*cap*4 <= n*103 B)
  __half* bufA  = (__half*)alloc((size_t)n * 64 * 4);
  __half* bufB  = (__half*)alloc((size_t)n * 64 * 4);
  int2*  offs2  = (int2*)alloc((size_t)n * 8);
  float* dinv   = (float*)alloc((size_t)n * 4);
  int*   csr    = (int*)alloc((size_t)nb * cap * 4);
  int*   bcur   = (int*)alloc(512 * 4);
  _Float16* PW1 = (_Float16*)alloc(4 * 4 * 64 * 8 * 2);  // CT=4, KT=4
  _Float16* PW2 = (_Float16*)alloc(4 * 2 * 64 * 8 * 2);  // CT=4, KT=2
  _Float16* PW3 = (_Float16*)alloc(3 * 2 * 64 * 8 * 2);  // CT=3, KT=2
  int*   binned = (int*)bufA;  // consumed by count_place before gemm1 writes bufA
  (void)ws_size; (void)n_in; (void)out_size;

  // fused: pack all three W matrices + zero bcur (one dispatch)
  pack_all_kernel<<<61, TPB, 0, stream>>>(W1, W2, W3, PW1, PW2, PW3, bcur);
  bin_kernel<<<nch, TPB, 0, stream>>>(rowA, colA, bcur, binned, e, nb, cap);
  count_place_kernel<<<nb, 512, 0, stream>>>(binned, bcur, cap, offs2, dinv, csr, n);

  int gmf = (n + 63) / 64;    // layer-1 GEMM: 64 rows/block
  int gagg = (n + 127) / 128; // agg kernels: 128 dests/block (2 per group)

  // L1 GEMM: bufA = (x @ W1) * dinv[row]
  gemm_mfma_f32in<128, 64, 4><<<gmf, TPB, 0, stream>>>(x, PW1, dinv, (_Float16*)bufA, n);
  // agg0 + gemm2 fused: bufB = (relu(L(bufA) + b1) @ W2) * dinv[row]
  fused_agg_gemm<64, 4, 0><<<gagg, 512, 0, stream>>>(
      (const uint4*)bufA, dinv, csr, offs2, b1, nullptr, PW2, bufB, n);
  // agg1: bufA = relu(L(bufB) + b2) * dinv[row]
  agg_mid_kernel<<<gagg, 512, 0, stream>>>((const uint4*)bufB, dinv, csr, offs2,
                                           b2, (uint4*)bufA, n);
  // agg2 + gemm3 fused: out = L(bufA) @ W3 + b3  (fp32)
  fused_agg_gemm<40, 3, 1><<<gagg, 512, 0, stream>>>(
      (const uint4*)bufA, dinv, csr, offs2, nullptr, b3, PW3, d_out, n);
}

// Round 8
// 312.241 us; speedup vs baseline: 1.1138x; 1.1138x over previous
//
#include <hip/hip_runtime.h>
#include <hip/hip_fp16.h>

constexpr int TPB = 256;
constexpr int SH = 9;          // bucket = 512 consecutive destinations
constexpr int BD = 1 << SH;    // 512 dests per bucket (max 512 buckets -> n <= 262144)
constexpr int CHUNK = 4096;    // edges per binning block
constexpr int RMASK = (1 << 23) - 1;  // row in low 23 bits, local dest in high 9

typedef _Float16 half8 __attribute__((ext_vector_type(8)));
typedef float float4v __attribute__((ext_vector_type(4)));

__device__ __forceinline__ int wave_incl_scan(int x, int lane) {
#pragma unroll
  for (int d = 1; d < 64; d <<= 1) {
    int y = __shfl_up(x, d);
    if (lane >= d) x += y;
  }
  return x;
}

// ---------------- binned CSR build (grouped by destination) ----------------
// Edge entries are packed ints: (local_dest_in_bucket << 23) | src_row.

__global__ void bin_kernel(const int* __restrict__ row, const int* __restrict__ col,
                           int* __restrict__ bcur, int* __restrict__ binned,
                           int e, int nb, int cap) {
  __shared__ int h[512];
  __shared__ int base[512];
  for (int i = threadIdx.x; i < nb; i += TPB) h[i] = 0;
  __syncthreads();
  int cb = blockIdx.x * CHUNK;
  int lim = min(cb + CHUNK, e);
  for (int i = cb + threadIdx.x; i < lim; i += TPB)
    atomicAdd(&h[col[i] >> SH], 1);
  __syncthreads();
  for (int i = threadIdx.x; i < nb; i += TPB) {
    int c = h[i];
    base[i] = c ? (i * cap + atomicAdd(&bcur[i], c)) : 0;
    h[i] = 0;  // reuse as local cursor
  }
  __syncthreads();
  for (int i = cb + threadIdx.x; i < lim; i += TPB) {
    int c = col[i];  // L2-hot re-read of this block's own chunk
    int b = c >> SH;
    int p = base[b] + atomicAdd(&h[b], 1);
    binned[p] = ((c & (BD - 1)) << 23) | row[i];
  }
}

// per bucket: fine counts -> scan -> offs2/dinv -> place (fused; binned stays L2-hot)
__global__ __launch_bounds__(512) void count_place_kernel(
    const int* __restrict__ binned, const int* __restrict__ bcnt, int cap,
    int2* __restrict__ offs2, float* __restrict__ dinv, int* __restrict__ csr, int n) {
  __shared__ int cnt[BD];
  __shared__ int wsum[8];
  int t = threadIdx.x, lane = t & 63, wv = t >> 6;
  int b = blockIdx.x;
  int c0 = b << SH;
  int ndst = min(BD, n - c0);
  cnt[t] = 0;
  __syncthreads();
  int beg = b * cap;
  int end = beg + bcnt[b];
  for (int i = beg + t; i < end; i += 512)
    atomicAdd(&cnt[(unsigned)binned[i] >> 23], 1);
  __syncthreads();
  int v = cnt[t];
  int ps = wave_incl_scan(v, lane);
  if (lane == 63) wsum[wv] = ps;
  __syncthreads();
  int woff = 0;
#pragma unroll
  for (int w = 0; w < 8; w++) woff += (w < wv) ? wsum[w] : 0;
  int ex = woff + ps - v;
  if (t < ndst) {
    offs2[c0 + t] = make_int2(beg + ex, beg + ex + v);
    dinv[c0 + t] = rsqrtf(1.0f + (float)v);  // deg = incoming + self-loop
  }
  __syncthreads();  // counts consumed; reuse cnt[] as cursors
  cnt[t] = beg + ex;
  __syncthreads();
  for (int i = beg + t; i < end; i += 512) {
    int pv = binned[i];
    int p = atomicAdd(&cnt[(unsigned)pv >> 23], 1);
    csr[p] = pv;  // packed entry passes through unchanged
  }
}

// ---------------- fused weight packing (+ bcur zero) ----------------

template <int K, int M, int CT, int KT>
__device__ __forceinline__ void pack_one(const float* __restrict__ W,
                                         _Float16* __restrict__ P, int idx) {
  if (idx >= CT * KT * 64 * 8) return;
  int j = idx & 7;
  int lane = (idx >> 3) & 63;
  int f = idx >> 9;
  int kt = f % KT, ct = f / KT;
  int c = ct * 16 + (lane & 15);
  int k = kt * 32 + (lane >> 4) * 8 + j;
  float v = (c < M) ? W[k * M + c] : 0.f;
  P[idx] = (_Float16)v;
}

__global__ __launch_bounds__(256) void pack_all_kernel(
    const float* __restrict__ W1, const float* __restrict__ W2,
    const float* __restrict__ W3, _Float16* __restrict__ P1,
    _Float16* __restrict__ P2, _Float16* __restrict__ P3, int* __restrict__ bcur) {
  int blk = blockIdx.x, t = threadIdx.x;
  if (blk < 32) {
    pack_one<128, 64, 4, 4>(W1, P1, blk * 256 + t);
  } else if (blk < 48) {
    pack_one<64, 64, 4, 2>(W2, P2, (blk - 32) * 256 + t);
  } else if (blk < 60) {
    pack_one<64, 40, 3, 2>(W3, P3, (blk - 48) * 256 + t);
  } else {
    bcur[t] = 0;
    bcur[t + 256] = 0;
  }
}

// ---------------- layer-1 MFMA GEMM (fp32 in, fp16 out, dinv pre-scale) -----

template <int K, int M, int CT>
__global__ __launch_bounds__(256) void gemm_mfma_f32in(const float* __restrict__ x,
                                                       const _Float16* __restrict__ PW,
                                                       const float* __restrict__ dinv,
                                                       _Float16* __restrict__ out, int n) {
  constexpr int KT = K / 32;
  int lane = threadIdx.x & 63, wv = threadIdx.x >> 6;
  int m = lane & 15, q = lane >> 4;
  int row0w = blockIdx.x * 64 + wv * 16;
  int arow = row0w + m;
  int ar = arow < n ? arow : n - 1;  // clamp; stores are guarded
  const half8* pw = (const half8*)PW;

  float4v acc[CT];
#pragma unroll
  for (int ct = 0; ct < CT; ct++) acc[ct] = (float4v){0.f, 0.f, 0.f, 0.f};

#pragma unroll
  for (int kt = 0; kt < KT; kt++) {
    const float* xp = x + (size_t)ar * K + kt * 32 + q * 8;
    float4 x0 = *(const float4*)xp;
    float4 x1 = *(const float4*)(xp + 4);
    half8 a;
    a[0] = (_Float16)x0.x; a[1] = (_Float16)x0.y;
    a[2] = (_Float16)x0.z; a[3] = (_Float16)x0.w;
    a[4] = (_Float16)x1.x; a[5] = (_Float16)x1.y;
    a[6] = (_Float16)x1.z; a[7] = (_Float16)x1.w;
#pragma unroll
    for (int ct = 0; ct < CT; ct++) {
      half8 b = pw[(ct * KT + kt) * 64 + lane];
      acc[ct] = __builtin_amdgcn_mfma_f32_16x16x32_f16(a, b, acc[ct], 0, 0, 0);
    }
  }
  // D layout: col = lane&15, row = q*4 + reg
  int r0 = row0w + q * 4;
  float dv[4];
#pragma unroll
  for (int reg = 0; reg < 4; reg++) dv[reg] = (r0 + reg < n) ? dinv[r0 + reg] : 0.f;
#pragma unroll
  for (int ct = 0; ct < CT; ct++) {
    int c = ct * 16 + m;
    if (c < M) {
#pragma unroll
      for (int reg = 0; reg < 4; reg++) {
        int r = r0 + reg;
        if (r < n) out[(size_t)r * M + c] = (_Float16)(acc[ct][reg] * dv[reg]);
      }
    }
  }
}

// ---------------- mid MFMA GEMM (fp16 in, fp16 out, dinv post-scale) --------

template <int K, int M, int CT>
__global__ __launch_bounds__(256) void gemm_mfma_f16in(const _Float16* __restrict__ x,
                                                       const _Float16* __restrict__ PW,
                                                       const float* __restrict__ dinv,
                                                       _Float16* __restrict__ out, int n) {
  constexpr int KT = K / 32;
  int lane = threadIdx.x & 63, wv = threadIdx.x >> 6;
  int m = lane & 15, q = lane >> 4;
  int row0w = blockIdx.x * 64 + wv * 16;
  int arow = row0w + m;
  int ar = arow < n ? arow : n - 1;
  const half8* pw = (const half8*)PW;

  float4v acc[CT];
#pragma unroll
  for (int ct = 0; ct < CT; ct++) acc[ct] = (float4v){0.f, 0.f, 0.f, 0.f};

#pragma unroll
  for (int kt = 0; kt < KT; kt++) {
    half8 a = *(const half8*)(x + (size_t)ar * K + kt * 32 + q * 8);
#pragma unroll
    for (int ct = 0; ct < CT; ct++) {
      half8 b = pw[(ct * KT + kt) * 64 + lane];
      acc[ct] = __builtin_amdgcn_mfma_f32_16x16x32_f16(a, b, acc[ct], 0, 0, 0);
    }
  }
  int r0 = row0w + q * 4;
  float dv[4];
#pragma unroll
  for (int reg = 0; reg < 4; reg++) dv[reg] = (r0 + reg < n) ? dinv[r0 + reg] : 0.f;
#pragma unroll
  for (int ct = 0; ct < CT; ct++) {
    int c = ct * 16 + m;
    if (c < M) {
#pragma unroll
      for (int reg = 0; reg < 4; reg++) {
        int r = r0 + reg;
        if (r < n) out[(size_t)r * M + c] = (_Float16)(acc[ct][reg] * dv[reg]);
      }
    }
  }
}

// ---------------- final MFMA GEMM (fp16 in, fp32 out, +bias) ----------------

template <int K, int M, int CT>
__global__ __launch_bounds__(256) void gemm_mfma_f16in_f32out(
    const _Float16* __restrict__ x, const _Float16* __restrict__ PW,
    const float* __restrict__ bias, float* __restrict__ out, int n) {
  constexpr int KT = K / 32;
  int lane = threadIdx.x & 63, wv = threadIdx.x >> 6;
  int m = lane & 15, q = lane >> 4;
  int row0w = blockIdx.x * 64 + wv * 16;
  int arow = row0w + m;
  int ar = arow < n ? arow : n - 1;
  const half8* pw = (const half8*)PW;

  float4v acc[CT];
#pragma unroll
  for (int ct = 0; ct < CT; ct++) acc[ct] = (float4v){0.f, 0.f, 0.f, 0.f};

#pragma unroll
  for (int kt = 0; kt < KT; kt++) {
    half8 a = *(const half8*)(x + (size_t)ar * K + kt * 32 + q * 8);
#pragma unroll
    for (int ct = 0; ct < CT; ct++) {
      half8 b = pw[(ct * KT + kt) * 64 + lane];
      acc[ct] = __builtin_amdgcn_mfma_f32_16x16x32_f16(a, b, acc[ct], 0, 0, 0);
    }
  }
  int r0 = row0w + q * 4;
#pragma unroll
  for (int ct = 0; ct < CT; ct++) {
    int c = ct * 16 + m;
    if (c < M) {
      float bb = bias[c];
#pragma unroll
      for (int reg = 0; reg < 4; reg++) {
        int r = r0 + reg;
        if (r < n) out[(size_t)r * M + c] = acc[ct][reg] + bb;
      }
    }
  }
}

// ---------------- aggregation: 1 dest per 8-lane group, batch-16 MLP --------
// 256 threads = 32 groups; group g exclusively owns dest base+g (3125 blocks:
// fine-grained grid, no barrier, no tail coupling). Per 16-edge batch:
// 16 independent dwordx4 gathers issue first (256B/lane in flight), THEN the
// next batch's csr indices load in-place over r[] (the issued gathers hold
// the old values), then accumulate. No atomics, no shfl, no LDS.

__device__ __forceinline__ void h8_unpack(uint4 u, float* f) {
  __half2 h0 = *(__half2*)&u.x, h1 = *(__half2*)&u.y;
  __half2 h2 = *(__half2*)&u.z, h3 = *(__half2*)&u.w;
  float2 f0 = __half22float2(h0), f1 = __half22float2(h1);
  float2 f2 = __half22float2(h2), f3 = __half22float2(h3);
  f[0] = f0.x; f[1] = f0.y; f[2] = f1.x; f[3] = f1.y;
  f[4] = f2.x; f[5] = f2.y; f[6] = f3.x; f[7] = f3.y;
}

__device__ __forceinline__ uint4 pack_h8v(const float* o) {
  __half2 h0 = __float22half2_rn(make_float2(o[0], o[1]));
  __half2 h1 = __float22half2_rn(make_float2(o[2], o[3]));
  __half2 h2 = __float22half2_rn(make_float2(o[4], o[5]));
  __half2 h3 = __float22half2_rn(make_float2(o[6], o[7]));
  uint4 u;
  u.x = *(unsigned*)&h0;
  u.y = *(unsigned*)&h1;
  u.z = *(unsigned*)&h2;
  u.w = *(unsigned*)&h3;
  return u;
}

// MODE 0: out = relu((acc+self)*di + bias)            (layer-1 -> h1)
// MODE 1: out = relu((acc+self)*di + bias) * di       (layer-2 -> h2*dinv)
// MODE 2: out = (acc+self)*di                         (layer-3 pre-GEMM, L(h2))
template <int MODE>
__global__ __launch_bounds__(256) void agg_dest_kernel(
    const uint4* __restrict__ xw4, const float* __restrict__ dinv,
    const int* __restrict__ csr, const int2* __restrict__ offs2,
    const float* __restrict__ bias, uint4* __restrict__ out4, int n) {
  int t = threadIdx.x;
  int g = t >> 3, fl = t & 7;
  int i = blockIdx.x * 32 + g;
  if (i >= n) return;
  int2 oe = offs2[i];  // group-broadcast load
  int beg = oe.x, end = oe.y;
  float acc[8] = {0.f, 0.f, 0.f, 0.f, 0.f, 0.f, 0.f, 0.f};

  int r[16];
#pragma unroll
  for (int j = 0; j < 16; j++) {
    int idx = beg + j;
    r[j] = (idx < end) ? (csr[idx] & RMASK) : 0;
  }
#pragma unroll 1
  for (int b = beg; b < end; b += 16) {
    int cnt = end - b;  // group-uniform
    // 1) issue all 16 gathers (addresses ready from previous iteration)
    uint4 u[16];
#pragma unroll
    for (int j = 0; j < 16; j++)
      if (j < cnt) u[j] = xw4[(size_t)r[j] * 8 + fl];
    // 2) load next batch's csr indices in place (u holds the old values)
    int bn = b + 16;
#pragma unroll
    for (int j = 0; j < 16; j++) {
      int idx = bn + j;
      r[j] = (idx < end) ? (csr[idx] & RMASK) : 0;
    }
    // 3) accumulate
#pragma unroll
    for (int j = 0; j < 16; j++) {
      if (j < cnt) {
        float f[8];
        h8_unpack(u[j], f);
#pragma unroll
        for (int k = 0; k < 8; k++) acc[k] += f[k];
      }
    }
  }

  // self-loop (row pre-scaled by its own dinv) + epilogue
  uint4 sv = xw4[(size_t)i * 8 + fl];
  float sf[8];
  h8_unpack(sv, sf);
  float di = dinv[i];
  float o[8];
  if (MODE < 2) {
    const float4* b4 = (const float4*)bias;
    float4 ba = b4[fl * 2], bb = b4[fl * 2 + 1];
    o[0] = fmaxf((acc[0] + sf[0]) * di + ba.x, 0.f);
    o[1] = fmaxf((acc[1] + sf[1]) * di + ba.y, 0.f);
    o[2] = fmaxf((acc[2] + sf[2]) * di + ba.z, 0.f);
    o[3] = fmaxf((acc[3] + sf[3]) * di + ba.w, 0.f);
    o[4] = fmaxf((acc[4] + sf[4]) * di + bb.x, 0.f);
    o[5] = fmaxf((acc[5] + sf[5]) * di + bb.y, 0.f);
    o[6] = fmaxf((acc[6] + sf[6]) * di + bb.z, 0.f);
    o[7] = fmaxf((acc[7] + sf[7]) * di + bb.w, 0.f);
    if (MODE == 1) {
#pragma unroll
      for (int k = 0; k < 8; k++) o[k] *= di;
    }
  } else {
#pragma unroll
    for (int k = 0; k < 8; k++) o[k] = (acc[k] + sf[k]) * di;
  }
  out4[(size_t)i * 8 + fl] = pack_h8v(o);
}

// ---------------- launcher ----------------

extern "C" void kernel_launch(void* const* d_in, const int* in_sizes, int n_in,
                              void* d_out, int out_size, void* d_ws, size_t ws_size,
                              hipStream_t stream) {
  const float* x  = (const float*)d_in[0];
  const int*   ei = (const int*)d_in[1];
  const float* W1 = (const float*)d_in[2];
  const float* b1 = (const float*)d_in[3];
  const float* W2 = (const float*)d_in[4];
  const float* b2 = (const float*)d_in[5];
  const float* W3 = (const float*)d_in[6];
  const float* b3 = (const float*)d_in[7];

  int n = in_sizes[0] / 128;
  int e = in_sizes[1] / 2;
  const int* rowA = ei;      // edge_index[0] = source
  const int* colA = ei + e;  // edge_index[1] = destination (segment id)

  int nb = (n + BD - 1) >> SH;  // buckets (<= 512)
  int meanb = e / nb;
  int cap = meanb + (meanb / 4 > 1024 ? meanb / 4 : 1024);  // >25 sigma slack
  int nch = (e + CHUNK - 1) / CHUNK;

  size_t off = 0;
  auto alloc = [&](size_t bytes) {
    void* p = (char*)d_ws + off;
    off += (bytes + 255) & ~(size_t)255;
    return p;
  };
  // bufA (n*128 B) also aliases the binned edge array (nb*cap*4 <= n*103 B)
  __half* bufA  = (__half*)alloc((size_t)n * 64 * 2);
  __half* bufB  = (__half*)alloc((size_t)n * 64 * 2);
  __half* bufC  = (__half*)alloc((size_t)n * 64 * 2);
  int2*  offs2  = (int2*)alloc((size_t)n * 8);
  float* dinv   = (float*)alloc((size_t)n * 4);
  int*   csr    = (int*)alloc((size_t)nb * cap * 4);
  int*   bcur   = (int*)alloc(512 * 4);
  _Float16* PW1 = (_Float16*)alloc(4 * 4 * 64 * 8 * 2);  // CT=4, KT=4
  _Float16* PW2 = (_Float16*)alloc(4 * 2 * 64 * 8 * 2);  // CT=4, KT=2
  _Float16* PW3 = (_Float16*)alloc(3 * 2 * 64 * 8 * 2);  // CT=3, KT=2
  int*   binned = (int*)bufA;  // consumed by count_place before gemm1 writes bufA
  (void)ws_size; (void)n_in; (void)out_size;

  // fused: pack all three W matrices + zero bcur (one dispatch)
  pack_all_kernel<<<61, TPB, 0, stream>>>(W1, W2, W3, PW1, PW2, PW3, bcur);
  bin_kernel<<<nch, TPB, 0, stream>>>(rowA, colA, bcur, binned, e, nb, cap);
  count_place_kernel<<<nb, 512, 0, stream>>>(binned, bcur, cap, offs2, dinv, csr, n);

  int gmf = (n + 63) / 64;   // GEMMs: 64 rows/block
  int gagg = (n + 31) / 32;  // agg: 32 dests/block, 1 per 8-lane group

  // L1 GEMM: bufA = (x @ W1) * dinv[row]
  gemm_mfma_f32in<128, 64, 4><<<gmf, TPB, 0, stream>>>(x, PW1, dinv, (_Float16*)bufA, n);
  // agg0: bufB = h1 = relu(L(bufA) + b1)
  agg_dest_kernel<0><<<gagg, TPB, 0, stream>>>((const uint4*)bufA, dinv, csr, offs2,
                                               b1, (uint4*)bufB, n);
  // L2 GEMM: bufC = (bufB @ W2) * dinv[row]
  gemm_mfma_f16in<64, 64, 4><<<gmf, TPB, 0, stream>>>((const _Float16*)bufB, PW2, dinv,
                                                      (_Float16*)bufC, n);
  // agg1: bufA = h2 * dinv = relu(L(bufC) + b2) * dinv
  agg_dest_kernel<1><<<gagg, TPB, 0, stream>>>((const uint4*)bufC, dinv, csr, offs2,
                                               b2, (uint4*)bufA, n);
  // agg2: bufB = L(h2)  (input pre-scaled by agg1)
  agg_dest_kernel<2><<<gagg, TPB, 0, stream>>>((const uint4*)bufA, dinv, csr, offs2,
                                               nullptr, (uint4*)bufB, n);
  // L3 GEMM: out = bufB @ W3 + b3  (fp32)
  gemm_mfma_f16in_f32out<64, 40, 3><<<gmf, TPB, 0, stream>>>((const _Float16*)bufB, PW3,
                                                             b3, (float*)d_out, n);
}

// Round 9
// 284.426 us; speedup vs baseline: 1.2227x; 1.0978x over previous
//
#include <hip/hip_runtime.h>
#include <hip/hip_fp16.h>

constexpr int TPB = 256;
constexpr int SH = 8;          // bucket = 256 consecutive destinations
constexpr int BD = 1 << SH;    // 256 dests per bucket (max 512 buckets -> n <= 131072)
constexpr int CHUNK = 4096;    // edges per binning block
constexpr int RMASK = (1 << 23) - 1;  // row in low 23 bits, local dest in high bits

typedef _Float16 half8 __attribute__((ext_vector_type(8)));
typedef float float4v __attribute__((ext_vector_type(4)));

__device__ __forceinline__ int wave_incl_scan(int x, int lane) {
#pragma unroll
  for (int d = 1; d < 64; d <<= 1) {
    int y = __shfl_up(x, d);
    if (lane >= d) x += y;
  }
  return x;
}

// ---------------- binned CSR build (grouped by destination) ----------------
// Edge entries are packed ints: (local_dest_in_bucket << 23) | src_row.
// Halves the staging traffic vs int2.

__global__ void bin_kernel(const int* __restrict__ row, const int* __restrict__ col,
                           int* __restrict__ bcur, int* __restrict__ binned,
                           int e, int nb, int cap) {
  __shared__ int h[512];
  __shared__ int base[512];
  for (int i = threadIdx.x; i < nb; i += TPB) h[i] = 0;
  __syncthreads();
  int cb = blockIdx.x * CHUNK;
  int lim = min(cb + CHUNK, e);
  for (int i = cb + threadIdx.x; i < lim; i += TPB)
    atomicAdd(&h[col[i] >> SH], 1);
  __syncthreads();
  for (int i = threadIdx.x; i < nb; i += TPB) {
    int c = h[i];
    base[i] = c ? (i * cap + atomicAdd(&bcur[i], c)) : 0;
    h[i] = 0;  // reuse as local cursor
  }
  __syncthreads();
  for (int i = cb + threadIdx.x; i < lim; i += TPB) {
    int c = col[i];  // L2-hot re-read of this block's own chunk
    int b = c >> SH;
    int p = base[b] + atomicAdd(&h[b], 1);
    binned[p] = ((c & (BD - 1)) << 23) | row[i];
  }
}

// per bucket: fine counts -> scan -> offs2/dinv -> place (fused; binned stays L2-hot)
// csr output stores the PLAIN row index (dest implicit in position).
__global__ __launch_bounds__(512) void count_place_kernel(
    const int* __restrict__ binned, const int* __restrict__ bcnt, int cap,
    int2* __restrict__ offs2, float* __restrict__ dinv, int* __restrict__ csr, int n) {
  __shared__ int cnt[BD];
  __shared__ int wsum[8];
  int t = threadIdx.x, lane = t & 63, wv = t >> 6;
  int b = blockIdx.x;
  int c0 = b << SH;
  int ndst = min(BD, n - c0);
  if (t < BD) cnt[t] = 0;
  __syncthreads();
  int beg = b * cap;
  int end = beg + bcnt[b];
  for (int i = beg + t; i < end; i += 512)
    atomicAdd(&cnt[(unsigned)binned[i] >> 23], 1);
  __syncthreads();
  int v = (t < BD) ? cnt[t] : 0;
  int ps = wave_incl_scan(v, lane);
  if (lane == 63) wsum[wv] = ps;
  __syncthreads();
  int woff = 0;
#pragma unroll
  for (int w = 0; w < 8; w++) woff += (w < wv) ? wsum[w] : 0;
  int ex = woff + ps - v;
  if (t < ndst) {
    offs2[c0 + t] = make_int2(beg + ex, beg + ex + v);
    dinv[c0 + t] = rsqrtf(1.0f + (float)v);  // deg = incoming + self-loop
  }
  __syncthreads();  // counts consumed; reuse cnt[] as cursors
  if (t < BD) cnt[t] = beg + ex;
  __syncthreads();
  for (int i = beg + t; i < end; i += 512) {
    int pv = binned[i];
    int p = atomicAdd(&cnt[(unsigned)pv >> 23], 1);
    csr[p] = pv & RMASK;  // plain row index for the agg kernels
  }
}

// ---------------- fused weight packing (+ bcur zero) ----------------

// Pack W[K,M] fp32 into B-fragment order for mfma_f32_16x16x32_f16:
// frag f = ct*KT+kt; lane holds B[k=kt*32+(lane>>4)*8+j][n=ct*16+(lane&15)].
template <int K, int M, int CT, int KT>
__device__ __forceinline__ void pack_one(const float* __restrict__ W,
                                         _Float16* __restrict__ P, int idx) {
  if (idx >= CT * KT * 64 * 8) return;
  int j = idx & 7;
  int lane = (idx >> 3) & 63;
  int f = idx >> 9;
  int kt = f % KT, ct = f / KT;
  int c = ct * 16 + (lane & 15);
  int k = kt * 32 + (lane >> 4) * 8 + j;
  float v = (c < M) ? W[k * M + c] : 0.f;
  P[idx] = (_Float16)v;
}

__global__ __launch_bounds__(256) void pack_all_kernel(
    const float* __restrict__ W1, const float* __restrict__ W2,
    const float* __restrict__ W3, _Float16* __restrict__ P1,
    _Float16* __restrict__ P2, _Float16* __restrict__ P3, int* __restrict__ bcur) {
  int blk = blockIdx.x, t = threadIdx.x;
  if (blk < 32) {
    pack_one<128, 64, 4, 4>(W1, P1, blk * 256 + t);
  } else if (blk < 48) {
    pack_one<64, 64, 4, 2>(W2, P2, (blk - 32) * 256 + t);
  } else if (blk < 60) {
    pack_one<64, 40, 3, 2>(W3, P3, (blk - 48) * 256 + t);
  } else {
    bcur[t] = 0;
    bcur[t + 256] = 0;
  }
}

// ---------------- layer-1 MFMA GEMM (fp32 in, fp16 out, dinv pre-scale) -----

template <int K, int M, int CT>
__global__ __launch_bounds__(256) void gemm_mfma_f32in(const float* __restrict__ x,
                                                       const _Float16* __restrict__ PW,
                                                       const float* __restrict__ dinv,
                                                       _Float16* __restrict__ out, int n) {
  constexpr int KT = K / 32;
  int lane = threadIdx.x & 63, wv = threadIdx.x >> 6;
  int m = lane & 15, q = lane >> 4;
  int row0w = blockIdx.x * 64 + wv * 16;
  int arow = row0w + m;
  int ar = arow < n ? arow : n - 1;  // clamp; stores are guarded
  const half8* pw = (const half8*)PW;

  float4v acc[CT];
#pragma unroll
  for (int ct = 0; ct < CT; ct++) acc[ct] = (float4v){0.f, 0.f, 0.f, 0.f};

#pragma unroll
  for (int kt = 0; kt < KT; kt++) {
    const float* xp = x + (size_t)ar * K + kt * 32 + q * 8;
    float4 x0 = *(const float4*)xp;
    float4 x1 = *(const float4*)(xp + 4);
    half8 a;
    a[0] = (_Float16)x0.x; a[1] = (_Float16)x0.y;
    a[2] = (_Float16)x0.z; a[3] = (_Float16)x0.w;
    a[4] = (_Float16)x1.x; a[5] = (_Float16)x1.y;
    a[6] = (_Float16)x1.z; a[7] = (_Float16)x1.w;
#pragma unroll
    for (int ct = 0; ct < CT; ct++) {
      half8 b = pw[(ct * KT + kt) * 64 + lane];
      acc[ct] = __builtin_amdgcn_mfma_f32_16x16x32_f16(a, b, acc[ct], 0, 0, 0);
    }
  }
  // D layout: col = lane&15, row = q*4 + reg
  int r0 = row0w + q * 4;
  float dv[4];
#pragma unroll
  for (int reg = 0; reg < 4; reg++) dv[reg] = (r0 + reg < n) ? dinv[r0 + reg] : 0.f;
#pragma unroll
  for (int ct = 0; ct < CT; ct++) {
    int c = ct * 16 + m;
    if (c < M) {
#pragma unroll
      for (int reg = 0; reg < 4; reg++) {
        int r = r0 + reg;
        if (r < n) out[(size_t)r * M + c] = (_Float16)(acc[ct][reg] * dv[reg]);
      }
    }
  }
}

// ---------------- half-slot aggregation core (ROUND-3 WINNER) ----------------
// 16-lane slot owns one node. Lanes split into two halves (fl16>>3); half h
// accumulates edges 2j+h of each 16-edge batch, so one dwordx4 gather
// instruction fetches 2 full 128B rows per slot. csr batch for the NEXT
// iteration is prefetched before the current gathers (latency overlap).
// NOTE: the __shfl broadcast MUST be unconditional — the ej<cnt predicate is
// non-uniform across the two halves; a shfl from an exec-masked-out source
// lane returns undefined data (round-2 bug).
// Caller must xor-8 merge the two halves' partial sums.

__device__ __forceinline__ void h8_add(uint4 u, float* acc) {
  __half2 h0 = *(__half2*)&u.x, h1 = *(__half2*)&u.y;
  __half2 h2 = *(__half2*)&u.z, h3 = *(__half2*)&u.w;
  float2 f0 = __half22float2(h0), f1 = __half22float2(h1);
  float2 f2 = __half22float2(h2), f3 = __half22float2(h3);
  acc[0] += f0.x; acc[1] += f0.y; acc[2] += f1.x; acc[3] += f1.y;
  acc[4] += f2.x; acc[5] += f2.y; acc[6] += f3.x; acc[7] += f3.y;
}

__device__ __forceinline__ uint4 pack_h8(const float* o) {
  __half2 h0 = __float22half2_rn(make_float2(o[0], o[1]));
  __half2 h1 = __float22half2_rn(make_float2(o[2], o[3]));
  __half2 h2 = __float22half2_rn(make_float2(o[4], o[5]));
  __half2 h3 = __float22half2_rn(make_float2(o[6], o[7]));
  uint4 u;
  u.x = *(unsigned*)&h0;
  u.y = *(unsigned*)&h1;
  u.z = *(unsigned*)&h2;
  u.w = *(unsigned*)&h3;
  return u;
}

__device__ __forceinline__ void agg_node(const uint4* __restrict__ xw4,
                                         const int* __restrict__ csr,
                                         int beg, int end, int sb, int half,
                                         int fl, int fl16, float* acc) {
  int b = beg;
  int idx0 = b + fl16;
  int rr = (idx0 < end) ? csr[idx0] : 0;
  while (b < end) {
    int bn = b + 16;
    int idxn = bn + fl16;
    int rn = (idxn < end) ? csr[idxn] : 0;  // prefetch next batch under gathers
    int cnt = end - b;                      // slot-uniform
    uint4 u[8];
    int r[8];
#pragma unroll
    for (int j = 0; j < 8; j++) {
      int ej = 2 * j + half;
      r[j] = __shfl(rr, sb + ej);  // unconditional: all slot lanes active
    }
#pragma unroll
    for (int j = 0; j < 8; j++) {
      int ej = 2 * j + half;
      if (ej < cnt) u[j] = xw4[(size_t)r[j] * 8 + fl];
    }
#pragma unroll
    for (int j = 0; j < 8; j++) {
      int ej = 2 * j + half;
      if (ej < cnt) h8_add(u[j], acc);
    }
    rr = rn;
    b = bn;
  }
}

// ---------------- standalone mid aggregation (layer-2) ----------------
// out = relu(acc*di + b2) * di   (pre-scaled for the layer-3 pre-agg)

__global__ __launch_bounds__(256) void agg_mid_kernel(
    const uint4* __restrict__ xw4, const float* __restrict__ dinv,
    const int* __restrict__ csr, const int2* __restrict__ offs2,
    const float* __restrict__ bias, uint4* __restrict__ out4, int n) {
  int lane = threadIdx.x & 63, wv = threadIdx.x >> 6;
  int sl = lane >> 4, fl16 = lane & 15, half = fl16 >> 3, fl = fl16 & 7;
  int sb = sl << 4;
  int i = blockIdx.x * 16 + wv * 4 + sl;
  bool valid = i < n;
  int ic = valid ? i : n - 1;
  int2 oe = offs2[ic];
  int beg = oe.x;
  int end = valid ? oe.y : beg;
  float di = dinv[ic];
  float acc[8] = {0.f, 0.f, 0.f, 0.f, 0.f, 0.f, 0.f, 0.f};
  if (!half) h8_add(xw4[(size_t)ic * 8 + fl], acc);  // self-loop (pre-scaled row)
  agg_node(xw4, csr, beg, end, sb, half, fl, fl16, acc);
#pragma unroll
  for (int k = 0; k < 8; k++) acc[k] += __shfl_xor(acc[k], 8);

  if (valid && !half) {
    const float4* b4 = (const float4*)bias;
    float4 ba = b4[fl * 2], bb = b4[fl * 2 + 1];
    float o[8];
    o[0] = fmaxf(acc[0] * di + ba.x, 0.f) * di;
    o[1] = fmaxf(acc[1] * di + ba.y, 0.f) * di;
    o[2] = fmaxf(acc[2] * di + ba.z, 0.f) * di;
    o[3] = fmaxf(acc[3] * di + ba.w, 0.f) * di;
    o[4] = fmaxf(acc[4] * di + bb.x, 0.f) * di;
    o[5] = fmaxf(acc[5] * di + bb.y, 0.f) * di;
    o[6] = fmaxf(acc[6] * di + bb.z, 0.f) * di;
    o[7] = fmaxf(acc[7] * di + bb.w, 0.f) * di;
    out4[(size_t)i * 8 + fl] = pack_h8(o);
  }
}

// ---------------- fused aggregation + MFMA GEMM ----------------
// Block owns 64 destination rows: 16 slots x 4 sequential nodes aggregate into
// an LDS fp16 tile (stride 72 halves = 144B), then 4 waves run the K=64 MFMA
// GEMM straight from LDS. offs2/dinv for all 4 nodes are prefetched before
// the node loop so inter-node serial gaps are hidden.
// FMODE 0 (layers 1->2): agg epilogue relu(acc*di + biasA); gemm out fp16 *dinv[r].
// FMODE 1 (layer 3):     agg epilogue acc*di;               gemm out fp32 + biasG.

template <int M, int CT, int FMODE>
__global__ __launch_bounds__(256) void fused_agg_gemm(
    const uint4* __restrict__ xw4, const float* __restrict__ dinv,
    const int* __restrict__ csr, const int2* __restrict__ offs2,
    const float* __restrict__ biasA, const float* __restrict__ biasG,
    const _Float16* __restrict__ PW, void* __restrict__ outp, int n) {
  constexpr int KT = 2;  // K = 64
  __shared__ _Float16 tile[64 * 72];
  int lane = threadIdx.x & 63, wv = threadIdx.x >> 6;
  int sl = lane >> 4, fl16 = lane & 15, half = fl16 >> 3, fl = fl16 & 7;
  int sb = sl << 4;
  int slot_id = wv * 4 + sl;  // 0..15
  int base = blockIdx.x * 64;

  // prefetch all 4 nodes' extents + dinv (independent loads, issue upfront)
  int ic4[4];
  int2 oe4[4];
  float di4[4];
#pragma unroll
  for (int nd = 0; nd < 4; nd++) {
    int i = base + slot_id * 4 + nd;
    ic4[nd] = (i < n) ? i : n - 1;
    oe4[nd] = offs2[ic4[nd]];
    di4[nd] = dinv[ic4[nd]];
  }

#pragma unroll 1
  for (int nd = 0; nd < 4; nd++) {
    int l = slot_id * 4 + nd;  // local row 0..63
    int i = base + l;
    bool valid = i < n;
    int ic = ic4[nd];
    int beg = oe4[nd].x;
    int end = valid ? oe4[nd].y : beg;
    float di = di4[nd];
    float acc[8] = {0.f, 0.f, 0.f, 0.f, 0.f, 0.f, 0.f, 0.f};
    if (!half) h8_add(xw4[(size_t)ic * 8 + fl], acc);  // self-loop
    agg_node(xw4, csr, beg, end, sb, half, fl, fl16, acc);
#pragma unroll
    for (int k = 0; k < 8; k++) acc[k] += __shfl_xor(acc[k], 8);

    float o[8];
    if (FMODE == 0) {
      const float4* b4 = (const float4*)biasA;
      float4 ba = b4[fl * 2], bb = b4[fl * 2 + 1];
      o[0] = fmaxf(acc[0] * di + ba.x, 0.f);
      o[1] = fmaxf(acc[1] * di + ba.y, 0.f);
      o[2] = fmaxf(acc[2] * di + ba.z, 0.f);
      o[3] = fmaxf(acc[3] * di + ba.w, 0.f);
      o[4] = fmaxf(acc[4] * di + bb.x, 0.f);
      o[5] = fmaxf(acc[5] * di + bb.y, 0.f);
      o[6] = fmaxf(acc[6] * di + bb.z, 0.f);
      o[7] = fmaxf(acc[7] * di + bb.w, 0.f);
    } else {
#pragma unroll
      for (int k = 0; k < 8; k++) o[k] = acc[k] * di;
    }
    if (!half) *(uint4*)&tile[(size_t)l * 72 + fl * 8] = pack_h8(o);
  }
  __syncthreads();

  // ---- MFMA phase (same fragment mapping as the standalone GEMMs) ----
  int m = lane & 15, q = lane >> 4;
  int lrow = wv * 16 + m;
  const half8* pw = (const half8*)PW;
  float4v accd[CT];
#pragma unroll
  for (int ct = 0; ct < CT; ct++) accd[ct] = (float4v){0.f, 0.f, 0.f, 0.f};
#pragma unroll
  for (int kt = 0; kt < KT; kt++) {
    half8 a = *(const half8*)&tile[lrow * 72 + kt * 32 + q * 8];
#pragma unroll
    for (int ct = 0; ct < CT; ct++) {
      half8 b = pw[(ct * KT + kt) * 64 + lane];
      accd[ct] = __builtin_amdgcn_mfma_f32_16x16x32_f16(a, b, accd[ct], 0, 0, 0);
    }
  }
  int r0 = base + wv * 16 + q * 4;
  if (FMODE == 0) {
    _Float16* out = (_Float16*)outp;
    float dv[4];
#pragma unroll
    for (int reg = 0; reg < 4; reg++) dv[reg] = (r0 + reg < n) ? dinv[r0 + reg] : 0.f;
#pragma unroll
    for (int ct = 0; ct < CT; ct++) {
      int c = ct * 16 + m;
      if (c < M) {
#pragma unroll
        for (int reg = 0; reg < 4; reg++) {
          int r = r0 + reg;
          if (r < n) out[(size_t)r * M + c] = (_Float16)(accd[ct][reg] * dv[reg]);
        }
      }
    }
  } else {
    float* out = (float*)outp;
#pragma unroll
    for (int ct = 0; ct < CT; ct++) {
      int c = ct * 16 + m;
      if (c < M) {
        float bb = biasG[c];
#pragma unroll
        for (int reg = 0; reg < 4; reg++) {
          int r = r0 + reg;
          if (r < n) out[(size_t)r * M + c] = accd[ct][reg] + bb;
        }
      }
    }
  }
}

// ---------------- launcher ----------------

extern "C" void kernel_launch(void* const* d_in, const int* in_sizes, int n_in,
                              void* d_out, int out_size, void* d_ws, size_t ws_size,
                              hipStream_t stream) {
  const float* x  = (const float*)d_in[0];
  const int*   ei = (const int*)d_in[1];
  const float* W1 = (const float*)d_in[2];
  const float* b1 = (const float*)d_in[3];
  const float* W2 = (const float*)d_in[4];
  const float* b2 = (const float*)d_in[5];
  const float* W3 = (const float*)d_in[6];
  const float* b3 = (const float*)d_in[7];

  int n = in_sizes[0] / 128;
  int e = in_sizes[1] / 2;
  const int* rowA = ei;      // edge_index[0] = source
  const int* colA = ei + e;  // edge_index[1] = destination (segment id)

  int nb = (n + BD - 1) >> SH;  // buckets (<= 512)
  int meanb = e / nb;
  int cap = meanb + (meanb / 4 > 1024 ? meanb / 4 : 1024);  // generous slack
  int nch = (e + CHUNK - 1) / CHUNK;

  size_t off = 0;
  auto alloc = [&](size_t bytes) {
    void* p = (char*)d_ws + off;
    off += (bytes + 255) & ~(size_t)255;
    return p;
  };
  // bufA (n*64*4 B) also aliases the binned edge array (nb*cap*4 << n*256 B)
  __half* bufA  = (__half*)alloc((size_t)n * 64 * 4);
  __half* bufB  = (__half*)alloc((size_t)n * 64 * 4);
  int2*  offs2  = (int2*)alloc((size_t)n * 8);
  float* dinv   = (float*)alloc((size_t)n * 4);
  int*   csr    = (int*)alloc((size_t)nb * cap * 4);
  int*   bcur   = (int*)alloc(512 * 4);
  _Float16* PW1 = (_Float16*)alloc(4 * 4 * 64 * 8 * 2);  // CT=4, KT=4
  _Float16* PW2 = (_Float16*)alloc(4 * 2 * 64 * 8 * 2);  // CT=4, KT=2
  _Float16* PW3 = (_Float16*)alloc(3 * 2 * 64 * 8 * 2);  // CT=3, KT=2
  int*   binned = (int*)bufA;  // consumed by count_place before gemm1 writes bufA
  (void)ws_size; (void)n_in; (void)out_size;

  // fused: pack all three W matrices + zero bcur (one dispatch)
  pack_all_kernel<<<61, TPB, 0, stream>>>(W1, W2, W3, PW1, PW2, PW3, bcur);
  bin_kernel<<<nch, TPB, 0, stream>>>(rowA, colA, bcur, binned, e, nb, cap);
  count_place_kernel<<<nb, 512, 0, stream>>>(binned, bcur, cap, offs2, dinv, csr, n);

  int gmf = (n + 63) / 64;   // 64 rows/block
  int gagg = (n + 15) / 16;  // 16 nodes/block (4 slots/wave x 4 waves)

  // L1 GEMM: bufA = (x @ W1) * dinv[row]
  gemm_mfma_f32in<128, 64, 4><<<gmf, TPB, 0, stream>>>(x, PW1, dinv, (_Float16*)bufA, n);
  // agg0 + gemm2 fused: bufB = (relu(L(bufA) + b1) @ W2) * dinv[row]
  fused_agg_gemm<64, 4, 0><<<gmf, TPB, 0, stream>>>(
      (const uint4*)bufA, dinv, csr, offs2, b1, nullptr, PW2, bufB, n);
  // agg1: bufA = relu(L(bufB) + b2) * dinv[row]
  agg_mid_kernel<<<gagg, TPB, 0, stream>>>((const uint4*)bufB, dinv, csr, offs2,
                                           b2, (uint4*)bufA, n);
  // agg2 + gemm3 fused: out = L(bufA) @ W3 + b3  (fp32)
  fused_agg_gemm<40, 3, 1><<<gmf, TPB, 0, stream>>>(
      (const uint4*)bufA, dinv, csr, offs2, nullptr, b3, PW3, d_out, n);
}

// Round 10
// 254.168 us; speedup vs baseline: 1.3683x; 1.1190x over previous
//
#include <hip/hip_runtime.h>
#include <hip/hip_fp16.h>

constexpr int TPB = 256;
constexpr int SH = 8;          // bucket = 256 consecutive destinations
constexpr int BD = 1 << SH;    // 256 dests per bucket (max 512 buckets -> n <= 131072)
constexpr int CHUNK = 4096;    // edges per binning block
constexpr int RMASK = (1 << 23) - 1;  // row in low 23 bits, local dest in high bits

typedef _Float16 half8 __attribute__((ext_vector_type(8)));
typedef float float4v __attribute__((ext_vector_type(4)));

__device__ __forceinline__ int wave_incl_scan(int x, int lane) {
#pragma unroll
  for (int d = 1; d < 64; d <<= 1) {
    int y = __shfl_up(x, d);
    if (lane >= d) x += y;
  }
  return x;
}

// ---------------- binned CSR build (grouped by destination) ----------------
// Edge entries are packed ints: (local_dest_in_bucket << 23) | src_row.
// Halves the staging traffic vs int2.

__global__ void bin_kernel(const int* __restrict__ row, const int* __restrict__ col,
                           int* __restrict__ bcur, int* __restrict__ binned,
                           int e, int nb, int cap) {
  __shared__ int h[512];
  __shared__ int base[512];
  for (int i = threadIdx.x; i < nb; i += TPB) h[i] = 0;
  __syncthreads();
  int cb = blockIdx.x * CHUNK;
  int lim = min(cb + CHUNK, e);
  for (int i = cb + threadIdx.x; i < lim; i += TPB)
    atomicAdd(&h[col[i] >> SH], 1);
  __syncthreads();
  for (int i = threadIdx.x; i < nb; i += TPB) {
    int c = h[i];
    base[i] = c ? (i * cap + atomicAdd(&bcur[i], c)) : 0;
    h[i] = 0;  // reuse as local cursor
  }
  __syncthreads();
  for (int i = cb + threadIdx.x; i < lim; i += TPB) {
    int c = col[i];  // L2-hot re-read of this block's own chunk
    int b = c >> SH;
    int p = base[b] + atomicAdd(&h[b], 1);
    binned[p] = ((c & (BD - 1)) << 23) | row[i];
  }
}

// per bucket: fine counts -> scan -> offs2/dinv -> place (fused; binned stays L2-hot)
// csr output stores the PLAIN row index (dest implicit in position).
__global__ __launch_bounds__(512) void count_place_kernel(
    const int* __restrict__ binned, const int* __restrict__ bcnt, int cap,
    int2* __restrict__ offs2, float* __restrict__ dinv, int* __restrict__ csr, int n) {
  __shared__ int cnt[BD];
  __shared__ int wsum[8];
  int t = threadIdx.x, lane = t & 63, wv = t >> 6;
  int b = blockIdx.x;
  int c0 = b << SH;
  int ndst = min(BD, n - c0);
  if (t < BD) cnt[t] = 0;
  __syncthreads();
  int beg = b * cap;
  int end = beg + bcnt[b];
  for (int i = beg + t; i < end; i += 512)
    atomicAdd(&cnt[(unsigned)binned[i] >> 23], 1);
  __syncthreads();
  int v = (t < BD) ? cnt[t] : 0;
  int ps = wave_incl_scan(v, lane);
  if (lane == 63) wsum[wv] = ps;
  __syncthreads();
  int woff = 0;
#pragma unroll
  for (int w = 0; w < 8; w++) woff += (w < wv) ? wsum[w] : 0;
  int ex = woff + ps - v;
  if (t < ndst) {
    offs2[c0 + t] = make_int2(beg + ex, beg + ex + v);
    dinv[c0 + t] = rsqrtf(1.0f + (float)v);  // deg = incoming + self-loop
  }
  __syncthreads();  // counts consumed; reuse cnt[] as cursors
  if (t < BD) cnt[t] = beg + ex;
  __syncthreads();
  for (int i = beg + t; i < end; i += 512) {
    int pv = binned[i];
    int p = atomicAdd(&cnt[(unsigned)pv >> 23], 1);
    csr[p] = pv & RMASK;  // plain row index for the agg kernels
  }
}

// ---------------- fused weight packing (+ bcur zero) ----------------

// Pack W[K,M] fp32 into B-fragment order for mfma_f32_16x16x32_f16:
// frag f = ct*KT+kt; lane holds B[k=kt*32+(lane>>4)*8+j][n=ct*16+(lane&15)].
template <int K, int M, int CT, int KT>
__device__ __forceinline__ void pack_one(const float* __restrict__ W,
                                         _Float16* __restrict__ P, int idx) {
  if (idx >= CT * KT * 64 * 8) return;
  int j = idx & 7;
  int lane = (idx >> 3) & 63;
  int f = idx >> 9;
  int kt = f % KT, ct = f / KT;
  int c = ct * 16 + (lane & 15);
  int k = kt * 32 + (lane >> 4) * 8 + j;
  float v = (c < M) ? W[k * M + c] : 0.f;
  P[idx] = (_Float16)v;
}

__global__ __launch_bounds__(256) void pack_all_kernel(
    const float* __restrict__ W1, const float* __restrict__ W2,
    const float* __restrict__ W3, _Float16* __restrict__ P1,
    _Float16* __restrict__ P2, _Float16* __restrict__ P3, int* __restrict__ bcur) {
  int blk = blockIdx.x, t = threadIdx.x;
  if (blk < 32) {
    pack_one<128, 64, 4, 4>(W1, P1, blk * 256 + t);
  } else if (blk < 48) {
    pack_one<64, 64, 4, 2>(W2, P2, (blk - 32) * 256 + t);
  } else if (blk < 60) {
    pack_one<64, 40, 3, 2>(W3, P3, (blk - 48) * 256 + t);
  } else {
    bcur[t] = 0;
    bcur[t + 256] = 0;
  }
}

// ---------------- layer-1 MFMA GEMM (fp32 in, fp16 out, dinv pre-scale) -----

template <int K, int M, int CT>
__global__ __launch_bounds__(256) void gemm_mfma_f32in(const float* __restrict__ x,
                                                       const _Float16* __restrict__ PW,
                                                       const float* __restrict__ dinv,
                                                       _Float16* __restrict__ out, int n) {
  constexpr int KT = K / 32;
  int lane = threadIdx.x & 63, wv = threadIdx.x >> 6;
  int m = lane & 15, q = lane >> 4;
  int row0w = blockIdx.x * 64 + wv * 16;
  int arow = row0w + m;
  int ar = arow < n ? arow : n - 1;  // clamp; stores are guarded
  const half8* pw = (const half8*)PW;

  float4v acc[CT];
#pragma unroll
  for (int ct = 0; ct < CT; ct++) acc[ct] = (float4v){0.f, 0.f, 0.f, 0.f};

#pragma unroll
  for (int kt = 0; kt < KT; kt++) {
    const float* xp = x + (size_t)ar * K + kt * 32 + q * 8;
    float4 x0 = *(const float4*)xp;
    float4 x1 = *(const float4*)(xp + 4);
    half8 a;
    a[0] = (_Float16)x0.x; a[1] = (_Float16)x0.y;
    a[2] = (_Float16)x0.z; a[3] = (_Float16)x0.w;
    a[4] = (_Float16)x1.x; a[5] = (_Float16)x1.y;
    a[6] = (_Float16)x1.z; a[7] = (_Float16)x1.w;
#pragma unroll
    for (int ct = 0; ct < CT; ct++) {
      half8 b = pw[(ct * KT + kt) * 64 + lane];
      acc[ct] = __builtin_amdgcn_mfma_f32_16x16x32_f16(a, b, acc[ct], 0, 0, 0);
    }
  }
  // D layout: col = lane&15, row = q*4 + reg
  int r0 = row0w + q * 4;
  float dv[4];
#pragma unroll
  for (int reg = 0; reg < 4; reg++) dv[reg] = (r0 + reg < n) ? dinv[r0 + reg] : 0.f;
#pragma unroll
  for (int ct = 0; ct < CT; ct++) {
    int c = ct * 16 + m;
    if (c < M) {
#pragma unroll
      for (int reg = 0; reg < 4; reg++) {
        int r = r0 + reg;
        if (r < n) out[(size_t)r * M + c] = (_Float16)(acc[ct][reg] * dv[reg]);
      }
    }
  }
}

// ---------------- half-slot aggregation core (ROUND-3 WINNER, verbatim) ------
// 16-lane slot owns one node. Lanes split into two halves (fl16>>3); half h
// accumulates edges 2j+h of each 16-edge batch, so one dwordx4 gather
// instruction fetches 2 full 128B rows per slot. csr batch for the NEXT
// iteration is prefetched before the current gathers (latency overlap).
// NOTE: the __shfl broadcast MUST be unconditional — the ej<cnt predicate is
// non-uniform across the two halves; a shfl from an exec-masked-out source
// lane returns undefined data (round-2 bug).
// Caller must xor-8 merge the two halves' partial sums.

__device__ __forceinline__ void h8_add(uint4 u, float* acc) {
  __half2 h0 = *(__half2*)&u.x, h1 = *(__half2*)&u.y;
  __half2 h2 = *(__half2*)&u.z, h3 = *(__half2*)&u.w;
  float2 f0 = __half22float2(h0), f1 = __half22float2(h1);
  float2 f2 = __half22float2(h2), f3 = __half22float2(h3);
  acc[0] += f0.x; acc[1] += f0.y; acc[2] += f1.x; acc[3] += f1.y;
  acc[4] += f2.x; acc[5] += f2.y; acc[6] += f3.x; acc[7] += f3.y;
}

__device__ __forceinline__ uint4 pack_h8(const float* o) {
  __half2 h0 = __float22half2_rn(make_float2(o[0], o[1]));
  __half2 h1 = __float22half2_rn(make_float2(o[2], o[3]));
  __half2 h2 = __float22half2_rn(make_float2(o[4], o[5]));
  __half2 h3 = __float22half2_rn(make_float2(o[6], o[7]));
  uint4 u;
  u.x = *(unsigned*)&h0;
  u.y = *(unsigned*)&h1;
  u.z = *(unsigned*)&h2;
  u.w = *(unsigned*)&h3;
  return u;
}

__device__ __forceinline__ void agg_node(const uint4* __restrict__ xw4,
                                         const int* __restrict__ csr,
                                         int beg, int end, int sb, int half,
                                         int fl, int fl16, float* acc) {
  int b = beg;
  int idx0 = b + fl16;
  int rr = (idx0 < end) ? csr[idx0] : 0;
  while (b < end) {
    int bn = b + 16;
    int idxn = bn + fl16;
    int rn = (idxn < end) ? csr[idxn] : 0;  // prefetch next batch under gathers
    int cnt = end - b;                      // slot-uniform
    uint4 u[8];
    int r[8];
#pragma unroll
    for (int j = 0; j < 8; j++) {
      int ej = 2 * j + half;
      r[j] = __shfl(rr, sb + ej);  // unconditional: all slot lanes active
    }
#pragma unroll
    for (int j = 0; j < 8; j++) {
      int ej = 2 * j + half;
      if (ej < cnt) u[j] = xw4[(size_t)r[j] * 8 + fl];
    }
#pragma unroll
    for (int j = 0; j < 8; j++) {
      int ej = 2 * j + half;
      if (ej < cnt) h8_add(u[j], acc);
    }
    rr = rn;
    b = bn;
  }
}

// ---------------- standalone mid aggregation (layer-2) ----------------
// out = relu(acc*di + b2) * di   (pre-scaled for the layer-3 pre-agg)

__global__ __launch_bounds__(256) void agg_mid_kernel(
    const uint4* __restrict__ xw4, const float* __restrict__ dinv,
    const int* __restrict__ csr, const int2* __restrict__ offs2,
    const float* __restrict__ bias, uint4* __restrict__ out4, int n) {
  int lane = threadIdx.x & 63, wv = threadIdx.x >> 6;
  int sl = lane >> 4, fl16 = lane & 15, half = fl16 >> 3, fl = fl16 & 7;
  int sb = sl << 4;
  int i = blockIdx.x * 16 + wv * 4 + sl;
  bool valid = i < n;
  int ic = valid ? i : n - 1;
  int2 oe = offs2[ic];
  int beg = oe.x;
  int end = valid ? oe.y : beg;
  float di = dinv[ic];
  float acc[8] = {0.f, 0.f, 0.f, 0.f, 0.f, 0.f, 0.f, 0.f};
  if (!half) h8_add(xw4[(size_t)ic * 8 + fl], acc);  // self-loop (pre-scaled row)
  agg_node(xw4, csr, beg, end, sb, half, fl, fl16, acc);
#pragma unroll
  for (int k = 0; k < 8; k++) acc[k] += __shfl_xor(acc[k], 8);

  if (valid && !half) {
    const float4* b4 = (const float4*)bias;
    float4 ba = b4[fl * 2], bb = b4[fl * 2 + 1];
    float o[8];
    o[0] = fmaxf(acc[0] * di + ba.x, 0.f) * di;
    o[1] = fmaxf(acc[1] * di + ba.y, 0.f) * di;
    o[2] = fmaxf(acc[2] * di + ba.z, 0.f) * di;
    o[3] = fmaxf(acc[3] * di + ba.w, 0.f) * di;
    o[4] = fmaxf(acc[4] * di + bb.x, 0.f) * di;
    o[5] = fmaxf(acc[5] * di + bb.y, 0.f) * di;
    o[6] = fmaxf(acc[6] * di + bb.z, 0.f) * di;
    o[7] = fmaxf(acc[7] * di + bb.w, 0.f) * di;
    out4[(size_t)i * 8 + fl] = pack_h8(o);
  }
}

// ---------------- fused aggregation + MFMA GEMM ----------------
// Block owns 64 destination rows: 16 slots x 4 sequential nodes aggregate into
// an LDS fp16 tile (stride 72 halves = 144B), then 4 waves run the K=64 MFMA
// GEMM straight from LDS. NOTE: no cross-node prefetch arrays — runtime-
// indexed register arrays in the un-unrolled node loop go to scratch
// (round-9 regression, −20 µs/kernel).
// FMODE 0 (layers 1->2): agg epilogue relu(acc*di + biasA); gemm out fp16 *dinv[r].
// FMODE 1 (layer 3):     agg epilogue acc*di;               gemm out fp32 + biasG.

template <int M, int CT, int FMODE>
__global__ __launch_bounds__(256) void fused_agg_gemm(
    const uint4* __restrict__ xw4, const float* __restrict__ dinv,
    const int* __restrict__ csr, const int2* __restrict__ offs2,
    const float* __restrict__ biasA, const float* __restrict__ biasG,
    const _Float16* __restrict__ PW, void* __restrict__ outp, int n) {
  constexpr int KT = 2;  // K = 64
  __shared__ _Float16 tile[64 * 72];
  int lane = threadIdx.x & 63, wv = threadIdx.x >> 6;
  int sl = lane >> 4, fl16 = lane & 15, half = fl16 >> 3, fl = fl16 & 7;
  int sb = sl << 4;
  int slot_id = wv * 4 + sl;  // 0..15
  int base = blockIdx.x * 64;

#pragma unroll 1
  for (int nd = 0; nd < 4; nd++) {
    int l = slot_id * 4 + nd;  // local row 0..63
    int i = base + l;
    bool valid = i < n;
    int ic = valid ? i : n - 1;
    int2 oe = offs2[ic];
    int beg = oe.x;
    int end = valid ? oe.y : beg;
    float di = dinv[ic];
    float acc[8] = {0.f, 0.f, 0.f, 0.f, 0.f, 0.f, 0.f, 0.f};
    if (!half) h8_add(xw4[(size_t)ic * 8 + fl], acc);  // self-loop
    agg_node(xw4, csr, beg, end, sb, half, fl, fl16, acc);
#pragma unroll
    for (int k = 0; k < 8; k++) acc[k] += __shfl_xor(acc[k], 8);

    float o[8];
    if (FMODE == 0) {
      const float4* b4 = (const float4*)biasA;
      float4 ba = b4[fl * 2], bb = b4[fl * 2 + 1];
      o[0] = fmaxf(acc[0] * di + ba.x, 0.f);
      o[1] = fmaxf(acc[1] * di + ba.y, 0.f);
      o[2] = fmaxf(acc[2] * di + ba.z, 0.f);
      o[3] = fmaxf(acc[3] * di + ba.w, 0.f);
      o[4] = fmaxf(acc[4] * di + bb.x, 0.f);
      o[5] = fmaxf(acc[5] * di + bb.y, 0.f);
      o[6] = fmaxf(acc[6] * di + bb.z, 0.f);
      o[7] = fmaxf(acc[7] * di + bb.w, 0.f);
    } else {
#pragma unroll
      for (int k = 0; k < 8; k++) o[k] = acc[k] * di;
    }
    if (!half) *(uint4*)&tile[(size_t)l * 72 + fl * 8] = pack_h8(o);
  }
  __syncthreads();

  // ---- MFMA phase (same fragment mapping as the standalone GEMMs) ----
  int m = lane & 15, q = lane >> 4;
  int lrow = wv * 16 + m;
  const half8* pw = (const half8*)PW;
  float4v accd[CT];
#pragma unroll
  for (int ct = 0; ct < CT; ct++) accd[ct] = (float4v){0.f, 0.f, 0.f, 0.f};
#pragma unroll
  for (int kt = 0; kt < KT; kt++) {
    half8 a = *(const half8*)&tile[lrow * 72 + kt * 32 + q * 8];
#pragma unroll
    for (int ct = 0; ct < CT; ct++) {
      half8 b = pw[(ct * KT + kt) * 64 + lane];
      accd[ct] = __builtin_amdgcn_mfma_f32_16x16x32_f16(a, b, accd[ct], 0, 0, 0);
    }
  }
  int r0 = base + wv * 16 + q * 4;
  if (FMODE == 0) {
    _Float16* out = (_Float16*)outp;
    float dv[4];
#pragma unroll
    for (int reg = 0; reg < 4; reg++) dv[reg] = (r0 + reg < n) ? dinv[r0 + reg] : 0.f;
#pragma unroll
    for (int ct = 0; ct < CT; ct++) {
      int c = ct * 16 + m;
      if (c < M) {
#pragma unroll
        for (int reg = 0; reg < 4; reg++) {
          int r = r0 + reg;
          if (r < n) out[(size_t)r * M + c] = (_Float16)(accd[ct][reg] * dv[reg]);
        }
      }
    }
  } else {
    float* out = (float*)outp;
#pragma unroll
    for (int ct = 0; ct < CT; ct++) {
      int c = ct * 16 + m;
      if (c < M) {
        float bb = biasG[c];
#pragma unroll
        for (int reg = 0; reg < 4; reg++) {
          int r = r0 + reg;
          if (r < n) out[(size_t)r * M + c] = accd[ct][reg] + bb;
        }
      }
    }
  }
}

// ---------------- launcher ----------------

extern "C" void kernel_launch(void* const* d_in, const int* in_sizes, int n_in,
                              void* d_out, int out_size, void* d_ws, size_t ws_size,
                              hipStream_t stream) {
  const float* x  = (const float*)d_in[0];
  const int*   ei = (const int*)d_in[1];
  const float* W1 = (const float*)d_in[2];
  const float* b1 = (const float*)d_in[3];
  const float* W2 = (const float*)d_in[4];
  const float* b2 = (const float*)d_in[5];
  const float* W3 = (const float*)d_in[6];
  const float* b3 = (const float*)d_in[7];

  int n = in_sizes[0] / 128;
  int e = in_sizes[1] / 2;
  const int* rowA = ei;      // edge_index[0] = source
  const int* colA = ei + e;  // edge_index[1] = destination (segment id)

  int nb = (n + BD - 1) >> SH;  // buckets (<= 512)
  int meanb = e / nb;
  int cap = meanb + (meanb / 4 > 1024 ? meanb / 4 : 1024);  // generous slack
  int nch = (e + CHUNK - 1) / CHUNK;

  size_t off = 0;
  auto alloc = [&](size_t bytes) {
    void* p = (char*)d_ws + off;
    off += (bytes + 255) & ~(size_t)255;
    return p;
  };
  // bufA (n*64*4 B) also aliases the binned edge array (nb*cap*4 << n*256 B)
  __half* bufA  = (__half*)alloc((size_t)n * 64 * 4);
  __half* bufB  = (__half*)alloc((size_t)n * 64 * 4);
  int2*  offs2  = (int2*)alloc((size_t)n * 8);
  float* dinv   = (float*)alloc((size_t)n * 4);
  int*   csr    = (int*)alloc((size_t)nb * cap * 4);
  int*   bcur   = (int*)alloc(512 * 4);
  _Float16* PW1 = (_Float16*)alloc(4 * 4 * 64 * 8 * 2);  // CT=4, KT=4
  _Float16* PW2 = (_Float16*)alloc(4 * 2 * 64 * 8 * 2);  // CT=4, KT=2
  _Float16* PW3 = (_Float16*)alloc(3 * 2 * 64 * 8 * 2);  // CT=3, KT=2
  int*   binned = (int*)bufA;  // consumed by count_place before gemm1 writes bufA
  (void)ws_size; (void)n_in; (void)out_size;

  // fused: pack all three W matrices + zero bcur (one dispatch)
  pack_all_kernel<<<61, TPB, 0, stream>>>(W1, W2, W3, PW1, PW2, PW3, bcur);
  bin_kernel<<<nch, TPB, 0, stream>>>(rowA, colA, bcur, binned, e, nb, cap);
  count_place_kernel<<<nb, 512, 0, stream>>>(binned, bcur, cap, offs2, dinv, csr, n);

  int gmf = (n + 63) / 64;   // 64 rows/block
  int gagg = (n + 15) / 16;  // 16 nodes/block (4 slots/wave x 4 waves)

  // L1 GEMM: bufA = (x @ W1) * dinv[row]
  gemm_mfma_f32in<128, 64, 4><<<gmf, TPB, 0, stream>>>(x, PW1, dinv, (_Float16*)bufA, n);
  // agg0 + gemm2 fused: bufB = (relu(L(bufA) + b1) @ W2) * dinv[row]
  fused_agg_gemm<64, 4, 0><<<gmf, TPB, 0, stream>>>(
      (const uint4*)bufA, dinv, csr, offs2, b1, nullptr, PW2, bufB, n);
  // agg1: bufA = relu(L(bufB) + b2) * dinv[row]
  agg_mid_kernel<<<gagg, TPB, 0, stream>>>((const uint4*)bufB, dinv, csr, offs2,
                                           b2, (uint4*)bufA, n);
  // agg2 + gemm3 fused: out = L(bufA) @ W3 + b3  (fp32)
  fused_agg_gemm<40, 3, 1><<<gmf, TPB, 0, stream>>>(
      (const uint4*)bufA, dinv, csr, offs2, nullptr, b3, PW3, d_out, n);
}